// Round 5
// baseline (220.129 us; speedup 1.0000x reference)
//
#include <hip/hip_runtime.h>
#include <hip/hip_bf16.h>

#define IN_DIM    1024
#define HEAD_DIM  64
#define NUM_HEADS 16
#define SEQ       4096

// 1/sqrt(64) * log2(e), folded into Q (fp32, pre-bf16-cast). Softmax via exp2.
#define QSCALE 0.18033688011112042f

typedef __bf16 bf16;
typedef __attribute__((ext_vector_type(4))) __bf16 bf16x4;
typedef __attribute__((ext_vector_type(8))) __bf16 bf16x8;
typedef __attribute__((ext_vector_type(4))) float floatx4;

__device__ __forceinline__ void async16(bf16* lds, const bf16* g) {
    __builtin_amdgcn_global_load_lds(
        (const __attribute__((address_space(1))) unsigned int*)g,
        (__attribute__((address_space(3))) unsigned int*)lds, 16, 0, 0);
}

// ---------------------------------------------------------------------------
// ws layout: hb @0 (8MB) | Wt @8MB (6MB, n-major) | Qb @14MB | Kb @22MB | Vt @30MB
// ---------------------------------------------------------------------------

__global__ void mha_conv_h(const float* __restrict__ h, bf16* __restrict__ hb) {
    int i = blockIdx.x * blockDim.x + threadIdx.x;
    float4 v = ((const float4*)h)[i];
    bf16x4 r;
    r[0] = (bf16)v.x; r[1] = (bf16)v.y; r[2] = (bf16)v.z; r[3] = (bf16)v.w;
    ((bf16x4*)hb)[i] = r;
}

__global__ void mha_conv_wt(const float* __restrict__ Wq, const float* __restrict__ Wk,
                            const float* __restrict__ Wv, bf16* __restrict__ Wt) {
    __shared__ bf16 tile[64][65];
    const int mat = blockIdx.z;
    const float* W = (mat == 0) ? Wq : (mat == 1) ? Wk : Wv;
    const int k0 = blockIdx.y * 64, n0 = blockIdx.x * 64;
    const int tn = threadIdx.x & 63, tq = threadIdx.x >> 6;
#pragma unroll
    for (int i = 0; i < 16; ++i) {
        int kk = tq + i * 4;
        tile[kk][tn] = (bf16)W[(size_t)(k0 + kk) * 1024 + n0 + tn];
    }
    __syncthreads();
#pragma unroll
    for (int i = 0; i < 16; ++i) {
        int nn = tq + i * 4;
        Wt[((size_t)mat << 20) + (size_t)(n0 + nn) * 1024 + k0 + tn] = tile[tn][nn];
    }
}

// ---------------------------------------------------------------------------
// QKV GEMM, 128x128 tile, BK=32, global_load_lds staging, XOR swizzle.
// For the V block-columns (mat==2) MFMA operands are SWAPPED so the output is
// V^T directly -> Vt[d][s] stores become coalesced (l16 -> s-contiguous).
// ---------------------------------------------------------------------------
__launch_bounds__(256)
__global__ void mha_qkv_gemm(const bf16* __restrict__ hb, const bf16* __restrict__ Wt,
                             const float* __restrict__ bq, const float* __restrict__ bk,
                             const float* __restrict__ bv,
                             bf16* __restrict__ Qb, bf16* __restrict__ Kb,
                             bf16* __restrict__ Vt) {
    __shared__ __align__(16) bf16 As[128 * 32];
    __shared__ __align__(16) bf16 Bs[128 * 32];

    const int lane = threadIdx.x & 63;
    const int wave = threadIdx.x >> 6;
    const int l16  = lane & 15;
    const int quad = lane >> 4;
    const int wm   = wave & 1;
    const int wn   = wave >> 1;

    const int m0  = blockIdx.x * 128;
    const int n0  = blockIdx.y * 128;
    const int mat = n0 >> 10;
    const int nc0 = n0 & 1023;

    const bf16* Wp = Wt + ((size_t)mat << 20);

    floatx4 acc[4][4] = {};
    const int swz = (l16 >> 1) & 3;
    const bool swap = (mat == 2);

    for (int k0 = 0; k0 < IN_DIM; k0 += 32) {
#pragma unroll
        for (int r = 0; r < 2; ++r) {
            int g = wave * 128 + r * 64 + lane;
            int row = g >> 2, c = g & 3;
            int gc = c ^ ((row >> 1) & 3);
            bf16* ldsbase_a = As + (size_t)(wave * 128 + r * 64) * 8;
            bf16* ldsbase_b = Bs + (size_t)(wave * 128 + r * 64) * 8;
            async16(ldsbase_a, hb + (size_t)(m0 + row) * IN_DIM + k0 + gc * 8);
            async16(ldsbase_b, Wp + (size_t)(nc0 + row) * IN_DIM + k0 + gc * 8);
        }
        __syncthreads();

        bf16x8 af[4], bf[4];
#pragma unroll
        for (int mt = 0; mt < 4; ++mt)
            af[mt] = *(const bf16x8*)(As + (size_t)(wm * 64 + mt * 16 + l16) * 32
                                      + ((quad ^ swz) * 8));
#pragma unroll
        for (int nt = 0; nt < 4; ++nt)
            bf[nt] = *(const bf16x8*)(Bs + (size_t)(wn * 64 + nt * 16 + l16) * 32
                                      + ((quad ^ swz) * 8));
        if (!swap) {
#pragma unroll
            for (int mt = 0; mt < 4; ++mt)
#pragma unroll
                for (int nt = 0; nt < 4; ++nt)
                    acc[mt][nt] = __builtin_amdgcn_mfma_f32_16x16x32_bf16(af[mt], bf[nt],
                                                                          acc[mt][nt], 0, 0, 0);
        } else {
#pragma unroll
            for (int mt = 0; mt < 4; ++mt)
#pragma unroll
                for (int nt = 0; nt < 4; ++nt)
                    acc[mt][nt] = __builtin_amdgcn_mfma_f32_16x16x32_bf16(bf[nt], af[mt],
                                                                          acc[mt][nt], 0, 0, 0);
        }
        __syncthreads();
    }

    if (!swap) {
        const float* bias = (mat == 0) ? bq : bk;
#pragma unroll
        for (int nt = 0; nt < 4; ++nt) {
            int nc = nc0 + wn * 64 + nt * 16 + l16;
            float bb = bias[nc];
            int head = nc >> 6, d = nc & 63;
#pragma unroll
            for (int mt = 0; mt < 4; ++mt)
#pragma unroll
                for (int r = 0; r < 4; ++r) {
                    int srow = m0 + wm * 64 + mt * 16 + quad * 4 + r;
                    float v = acc[mt][nt][r] + bb;
                    if (mat == 0)
                        Qb[((size_t)head * SEQ + srow) * HEAD_DIM + d] = (bf16)(v * QSCALE);
                    else
                        Kb[((size_t)head * SEQ + srow) * HEAD_DIM + d] = (bf16)v;
                }
        }
    } else {
        // acc[mt][nt] holds D rows = n (d-dim), cols = m (s-dim)
#pragma unroll
        for (int nt = 0; nt < 4; ++nt)
#pragma unroll
            for (int r = 0; r < 4; ++r) {
                int n = nc0 + wn * 64 + nt * 16 + quad * 4 + r;   // d index 0..1023
                float bb = bv[n];
                int head = n >> 6, d = n & 63;
#pragma unroll
                for (int mt = 0; mt < 4; ++mt) {
                    int s = m0 + wm * 64 + mt * 16 + l16;
                    Vt[((size_t)head * 64 + d) * SEQ + s] = (bf16)(acc[mt][nt][r] + bb);
                }
            }
    }
}

// ---------------------------------------------------------------------------
// Attention: 512 threads = 8 waves x 16 q-rows. Software-pipelined:
// each barrier interval computes S(t) [MFMA->exp2->P write] AND PV(t-1)
// [P read->MFMA] -- two independent streams per wave.
// Slots: K x2, V x3 (written t+1, read t-1), P x2. LDS = 76 KB, 2 blocks/CU.
// ---------------------------------------------------------------------------
__launch_bounds__(512, 4)
__global__ void mha_attn(const bf16* __restrict__ Qb, const bf16* __restrict__ Kb,
                         const bf16* __restrict__ Vt, float* __restrict__ out) {
    __shared__ __align__(16) bf16 Ks[2][64 * 64];       // 16 KB
    __shared__ __align__(16) bf16 Vs[3][64 * 64];       // 24 KB
    __shared__ __align__(16) bf16 Ps[2][8][16 * 72];    // 36 KB

    const int lane = threadIdx.x & 63;
    const int wave = threadIdx.x >> 6;
    const int l16  = lane & 15;
    const int quad = lane >> 4;

    const int hh    = blockIdx.y;
    const int qbase = blockIdx.x * 128 + wave * 16;

    const bf16* Qh = Qb + (size_t)hh * SEQ * HEAD_DIM;
    const bf16* Kh = Kb + (size_t)hh * SEQ * HEAD_DIM;
    const bf16* Vh = Vt + (size_t)hh * HEAD_DIM * SEQ;

    const int sg   = wave * 64 + lane;           // 512 16B-chunks per 64x64 tile
    const int srow = sg >> 3;
    const int sgc  = (sg & 7) ^ (srow & 7);

    bf16x8 qf[2];
#pragma unroll
    for (int ks = 0; ks < 2; ++ks)
        qf[ks] = *(const bf16x8*)(Qh + (size_t)(qbase + l16) * HEAD_DIM + ks * 32 + quad * 8);

    bf16x8 vone;
#pragma unroll
    for (int i = 0; i < 8; ++i) vone[i] = (bf16)1.0f;

    floatx4 o[4] = {};
    floatx4 ol   = {};

    const int swk = l16 & 7;

    // helper lambdas ---------------------------------------------------------
    auto stageK = [&](int slot, int t) {
        async16(&Ks[slot][wave * 512], Kh + (size_t)(t * 64 + srow) * HEAD_DIM + sgc * 8);
    };
    auto stageV = [&](int slot, int t) {
        async16(&Vs[slot][wave * 512], Vh + (size_t)srow * SEQ + t * 64 + sgc * 8);
    };
    auto doS = [&](int kslot, int pslot) {
        bf16* lp = &Ps[pslot][wave][0];
#pragma unroll
        for (int tt = 0; tt < 4; ++tt) {
            bf16x8 k0 = *(const bf16x8*)(&Ks[kslot][(size_t)(tt * 16 + l16) * 64
                                         + ((quad ^ swk) * 8)]);
            bf16x8 k1 = *(const bf16x8*)(&Ks[kslot][(size_t)(tt * 16 + l16) * 64
                                         + (((4 + quad) ^ swk) * 8)]);
            floatx4 s = {};
            s = __builtin_amdgcn_mfma_f32_16x16x32_bf16(k0, qf[0], s, 0, 0, 0);
            s = __builtin_amdgcn_mfma_f32_16x16x32_bf16(k1, qf[1], s, 0, 0, 0);
            bf16x4 pk;
#pragma unroll
            for (int r = 0; r < 4; ++r) pk[r] = (bf16)__builtin_amdgcn_exp2f(s[r]);
            *(bf16x4*)(lp + l16 * 72 + tt * 16 + quad * 4) = pk;
        }
    };
    auto doPV = [&](int vslot, int pslot) {
        bf16* lp = &Ps[pslot][wave][0];
#pragma unroll
        for (int ks = 0; ks < 2; ++ks) {
            bf16x8 pf = *(const bf16x8*)(lp + l16 * 72 + ks * 32 + quad * 8);
#pragma unroll
            for (int dt = 0; dt < 4; ++dt) {
                bf16x8 vf = *(const bf16x8*)(&Vs[vslot][(size_t)(dt * 16 + l16) * 64
                                             + (((ks * 4 + quad) ^ swk) * 8)]);
                o[dt] = __builtin_amdgcn_mfma_f32_16x16x32_bf16(pf, vf, o[dt], 0, 0, 0);
            }
            ol = __builtin_amdgcn_mfma_f32_16x16x32_bf16(pf, vone, ol, 0, 0, 0);
        }
    };
    // ------------------------------------------------------------------------

    stageK(0, 0); stageV(0, 0);
    __syncthreads();

    // iter 0: prefetch tile1, S(0)
    stageK(1, 1); stageV(1, 1);
    doS(0, 0);
    __syncthreads();

    int ivw = 2;   // V write slot = (t+1)%3 at t=1
    int ivr = 0;   // V read slot  = (t-1)%3 at t=1
    for (int t = 1; t < 64; ++t) {
        const int par = t & 1;
        if (t < 63) { stageK(par ^ 1, t + 1); stageV(ivw, t + 1); }
        doS(par, par);          // S(t): K slot t&1 -> P slot t&1
        doPV(ivr, par ^ 1);     // PV(t-1): V slot (t-1)%3, P slot (t-1)&1
        __syncthreads();
        ivw = (ivw == 2) ? 0 : ivw + 1;
        ivr = (ivr == 2) ? 0 : ivr + 1;
    }
    doPV(0, 1);                 // PV(63): V slot 63%3=0, P slot 1

#pragma unroll
    for (int r = 0; r < 4; ++r) {
        float inv = 1.0f / ol[r];
        int srow_o = qbase + quad * 4 + r;
#pragma unroll
        for (int dt = 0; dt < 4; ++dt)
            out[(size_t)srow_o * (NUM_HEADS * HEAD_DIM) + hh * 64 + dt * 16 + l16]
                = o[dt][r] * inv;
    }
}

extern "C" void kernel_launch(void* const* d_in, const int* in_sizes, int n_in,
                              void* d_out, int out_size, void* d_ws, size_t ws_size,
                              hipStream_t stream) {
    const float* h  = (const float*)d_in[0];
    const float* Wq = (const float*)d_in[1];
    const float* Wk = (const float*)d_in[2];
    const float* Wv = (const float*)d_in[3];
    const float* bq = (const float*)d_in[4];
    const float* bk = (const float*)d_in[5];
    const float* bv = (const float*)d_in[6];
    float* out = (float*)d_out;

    char* ws = (char*)d_ws;
    const size_t MB = 1024 * 1024;
    bf16* hb = (bf16*)(ws);
    bf16* Wt = (bf16*)(ws + 8 * MB);
    bf16* Qb = (bf16*)(ws + 14 * MB);
    bf16* Kb = (bf16*)(ws + 22 * MB);
    bf16* Vt = (bf16*)(ws + 30 * MB);

    mha_conv_h<<<(SEQ * IN_DIM / 4) / 256, 256, 0, stream>>>(h, hb);
    mha_conv_wt<<<dim3(16, 16, 3), 256, 0, stream>>>(Wq, Wk, Wv, Wt);
    mha_qkv_gemm<<<dim3(SEQ / 128, (3 * IN_DIM) / 128), 256, 0, stream>>>(
        hb, Wt, bq, bk, bv, Qb, Kb, Vt);
    mha_attn<<<dim3(SEQ / 128, NUM_HEADS), 512, 0, stream>>>(Qb, Kb, Vt, out);
}